// Round 8
// baseline (90.056 us; speedup 1.0000x reference)
//
#include <hip/hip_runtime.h>

#define B   64
#define C   128
#define H   56
#define HW  3136      // 56*56
#define HW4 784       // HW/4
#define NEG_INF (-3.402823466e38f)

// ---------------- wave-local peak rounds (verified absmax=0, R3-R7) --------
template<int TYPE>
__device__ void rounds_body(const float* __restrict__ S,
                            const int* __restrict__ scale,
                            float* __restrict__ out, int b) {
    constexpr int K    = (TYPE == 0) ? 3 : 2;
    constexpr int Hs   = H - K + 1;              // 54 / 55
    constexpr int n    = Hs * Hs;                // 2916 / 3025
    constexpr int half = (TYPE == 0) ? 112 : 56;
    constexpr int NJ   = (n + 63) / 64;          // 46 / 48

    const int lane = threadIdx.x & 63;

    float av[NJ];
    #pragma unroll
    for (int j = 0; j < NJ; ++j) {
        int i = lane + 64 * j;
        if (i < n) {
            int r = i / Hs, c = i - (i / Hs) * Hs;
            float s = 0.f;
            #pragma unroll
            for (int dr = 0; dr < K; ++dr)
                #pragma unroll
                for (int dc = 0; dc < K; ++dc)
                    s += S[(r + dr) * H + (c + dc)];
            av[j] = s / (float)(K * K);
        } else {
            av[j] = NEG_INF;
        }
    }

    for (int p = 0; p < 3; ++p) {
        float bv = NEG_INF; int bi = 0x7fffffff;
        #pragma unroll
        for (int j = 0; j < NJ; ++j) {
            int i = lane + 64 * j;
            if (av[j] > bv) { bv = av[j]; bi = i; }
        }
        #pragma unroll
        for (int d = 1; d < 64; d <<= 1) {
            float ov = __shfl_xor(bv, d);
            int   oi = __shfl_xor(bi, d);
            if (ov > bv || (ov == bv && oi < bi)) { bv = ov; bi = oi; }
        }
        const float vmax = bv;
        const int   idx  = bi;

        if (lane == 0) {
            int lr = idx / Hs, lc = idx - (idx / Hs) * Hs;
            int pg = TYPE * 3 + p;
            out[1536 + (b * 6 + pg) * 2 + 0] = (float)lr;
            out[1536 + (b * 6 + pg) * 2 + 1] = (float)lc;
            out[2304 + b * 6 + pg] = vmax;

            int s0 = scale[b * 2 + 0], s1 = scale[b * 2 + 1];
            int smin = s0 < s1 ? s0 : s1;
            int sb0 = (s0 - smin) >> 1, sb1 = (s1 - smin) >> 1;
            float rate_h = (float)(2 * lr + H - Hs + 1) / (2.0f * H);
            float rate_w = (float)(2 * lc + H - Hs + 1) / (2.0f * H);
            int c0 = (int)__fadd_rn((float)sb0, __fmul_rn((float)smin, rate_h));
            int c1 = (int)__fadd_rn((float)sb1, __fmul_rn((float)smin, rate_w));
            int top = c0 - half, bot = c0 + half;
            int lef = c1 - half, rig = c1 + half;
            int bel0 = top < 0 ? top : 0, bel1 = lef < 0 ? lef : 0;
            top -= bel0; bot -= bel0; lef -= bel1; rig -= bel1;
            int ov0 = (bot - s0 > 0) ? (bot - s0) : 0;
            int ov1 = (rig - s1 > 0) ? (rig - s1) : 0;
            top = (top - ov0 > 0) ? (top - ov0) : 0;
            lef = (lef - ov1 > 0) ? (lef - ov1) : 0;
            bot -= ov0; rig -= ov1;
            float* il = out + (size_t)(b * 6 + pg) * 4;
            il[0] = (float)top; il[1] = (float)lef;
            il[2] = (float)bot; il[3] = (float)rig;
        }

        if (p < 2) {
            #pragma unroll
            for (int j = 0; j < NJ; ++j) {
                unsigned long long m = __ballot(av[j] == vmax);
                while (m) {
                    int hl = __ffsll(m) - 1;
                    m &= m - 1;
                    int hidx = hl + 64 * j;
                    int hr = hidx / Hs, hc = hidx - (hidx / Hs) * Hs;
                    #pragma unroll
                    for (int jj = 0; jj < NJ; ++jj) {
                        int i = lane + 64 * jj;
                        int r = i / Hs, c = i - (i / Hs) * Hs;
                        bool inbox = (i < n) & (r >= hr - 1) & (r <= hr + 1)
                                             & (c >= hc - 1) & (c <= hc + 1);
                        if (inbox) av[jj] = 0.f;
                    }
                }
            }
        }
    }
}

// ---------------- single fused kernel: per-batch block, no cross-block sync -
// grid = 64 blocks x 1024 threads. Threads 0..783 each own one float4
// pixel-group, sum all 128 channels of their batch directly from fm
// (ascending c -> bit-identical S to the verified R5 pipeline), write to LDS.
// One barrier; waves 0/1 run the verified rounds. No global S, no 2nd launch.
__global__ __launch_bounds__(1024) void patch5_kernel(const float4* __restrict__ fm,
                                                      const int* __restrict__ scale,
                                                      float* __restrict__ out) {
    __shared__ float S[HW];
    const int b   = blockIdx.x;
    const int tid = threadIdx.x;

    if (tid < HW4) {
        const float4* base = fm + (size_t)b * C * HW4 + tid;
        float x = 0.f, y = 0.f, z = 0.f, w = 0.f;
        #pragma unroll 8
        for (int c = 0; c < C; ++c) {
            float4 v = base[(size_t)c * HW4];
            x += v.x; y += v.y; z += v.z; w += v.w;
        }
        reinterpret_cast<float4*>(S)[tid] = make_float4(x, y, z, w);
    }
    __syncthreads();   // the only barrier

    const int wave = tid >> 6;
    if (wave == 0)      rounds_body<0>(S, scale, out, b);
    else if (wave == 1) rounds_body<1>(S, scale, out, b);
    // waves 2..15 retire
}

extern "C" void kernel_launch(void* const* d_in, const int* in_sizes, int n_in,
                              void* d_out, int out_size, void* d_ws, size_t ws_size,
                              hipStream_t stream) {
    const float* fm    = (const float*)d_in[0];
    const int*   scale = (const int*)d_in[1];
    float*       out   = (float*)d_out;

    hipLaunchKernelGGL(patch5_kernel, dim3(B), dim3(1024), 0, stream,
                       (const float4*)fm, scale, out);
}

// Round 9
// 31.541 us; speedup vs baseline: 2.8552x; 2.8552x over previous
//
#include <hip/hip_runtime.h>

#define B   64
#define C   128
#define H   56
#define HW  3136      // 56*56
#define HW4 784       // HW/4
#define NF4 (B * HW4) // 50176 float4 S-elements total
#define NEG_INF (-3.402823466e38f)

// ---------------- Kernel 1: direct channel sum (proven at HBM roofline) ----
__global__ __launch_bounds__(256) void chansum_kernel(const float4* __restrict__ fm,
                                                      float4* __restrict__ S4) {
    int flat = blockIdx.x * 256 + threadIdx.x;     // 0..50175
    int b = flat / HW4;
    int g = flat - b * HW4;
    const float4* base = fm + (size_t)b * C * HW4 + g;
    float x = 0.f, y = 0.f, z = 0.f, w = 0.f;
    #pragma unroll 8
    for (int c = 0; c < C; ++c) {
        float4 v = base[(size_t)c * HW4];
        x += v.x; y += v.y; z += v.z; w += v.w;
    }
    S4[flat] = make_float4(x, y, z, w);
}

// ---------------- Kernel 2 body: LDS pooled map + small-code rounds ---------
// All scan/erase loops are RUNTIME loops -> few-KB code (R8 diagnosis: the
// old fully-unrolled register erase was ~100s of KB, instruction-fetch-bound).
template<int TYPE>
__device__ void peaks_body(const float* __restrict__ S, float* __restrict__ A,
                           const int* __restrict__ scale,
                           float* __restrict__ out, int b) {
    constexpr int K    = (TYPE == 0) ? 3 : 2;
    constexpr int Hs   = H - K + 1;              // 54 / 55
    constexpr int n    = Hs * Hs;                // 2916 / 3025
    constexpr int half = (TYPE == 0) ? 112 : 56;
    constexpr int NJ   = (n + 63) / 64;          // 46 / 48

    const int tid = threadIdx.x;

    // build pooled map in LDS; dr-major add order bit-identical to the
    // verified pipeline; true IEEE division by K*K.
    for (int i = tid; i < n; i += 256) {
        int r = i / Hs, c = i - (i / Hs) * Hs;
        float s = 0.f;
        for (int dr = 0; dr < K; ++dr)
            for (int dc = 0; dc < K; ++dc)
                s += S[(r + dr) * H + (c + dc)];
        A[i] = s / (float)(K * K);
    }
    __syncthreads();

    if (tid >= 64) return;            // wave 0 runs the rounds; 1-3 retire
    const int lane = tid;

    for (int p = 0; p < 3; ++p) {
        // argmax scan (strict '>' + ascending index = first occurrence)
        float bv = NEG_INF; int bi = 0x7fffffff;
        for (int j = 0; j < NJ; ++j) {
            int i = lane + 64 * j;
            float v = (i < n) ? A[i] : NEG_INF;
            if (v > bv) { bv = v; bi = i; }
        }
        // 64-lane butterfly, tie-break min index (verified R3-R8)
        #pragma unroll
        for (int d = 1; d < 64; d <<= 1) {
            float ov = __shfl_xor(bv, d);
            int   oi = __shfl_xor(bi, d);
            if (ov > bv || (ov == bv && oi < bi)) { bv = ov; bi = oi; }
        }
        const float vmax = bv;
        const int   idx  = bi;

        if (lane == 0) {
            int lr = idx / Hs, lc = idx - (idx / Hs) * Hs;
            int pg = TYPE * 3 + p;
            out[1536 + (b * 6 + pg) * 2 + 0] = (float)lr;
            out[1536 + (b * 6 + pg) * 2 + 1] = (float)lc;
            out[2304 + b * 6 + pg] = vmax;

            int s0 = scale[b * 2 + 0], s1 = scale[b * 2 + 1];
            int smin = s0 < s1 ? s0 : s1;
            int sb0 = (s0 - smin) >> 1, sb1 = (s1 - smin) >> 1;
            float rate_h = (float)(2 * lr + H - Hs + 1) / (2.0f * H);
            float rate_w = (float)(2 * lc + H - Hs + 1) / (2.0f * H);
            int c0 = (int)__fadd_rn((float)sb0, __fmul_rn((float)smin, rate_h));
            int c1 = (int)__fadd_rn((float)sb1, __fmul_rn((float)smin, rate_w));
            int top = c0 - half, bot = c0 + half;
            int lef = c1 - half, rig = c1 + half;
            int bel0 = top < 0 ? top : 0, bel1 = lef < 0 ? lef : 0;
            top -= bel0; bot -= bel0; lef -= bel1; rig -= bel1;
            int ov0 = (bot - s0 > 0) ? (bot - s0) : 0;
            int ov1 = (rig - s1 > 0) ? (rig - s1) : 0;
            top = (top - ov0 > 0) ? (top - ov0) : 0;
            lef = (lef - ov1 > 0) ? (lef - ov1) : 0;
            bot -= ov0; rig -= ov1;
            float* il = out + (size_t)(b * 6 + pg) * 4;
            il[0] = (float)top; il[1] = (float)lef;
            il[2] = (float)bot; il[3] = (float)rig;
        }

        if (p < 2) {
            // pass 1: per-lane equality mask, read strictly PRE-erase
            unsigned long long mymask = 0ull;
            for (int j = 0; j < NJ; ++j) {
                int i = lane + 64 * j;
                if (i < n && A[i] == vmax) mymask |= (1ull << j);
            }
            // pass 2: ballot hits; 9 lanes zero the clipped 3x3 box in LDS
            for (int j = 0; j < NJ; ++j) {
                unsigned long long m = __ballot((mymask >> j) & 1ull);
                while (m) {
                    int hl = __ffsll((long long)m) - 1;
                    m &= m - 1;
                    int q  = hl + 64 * j;
                    int hr = q / Hs, hc = q - (q / Hs) * Hs;
                    if (lane < 9) {
                        int rr = hr + lane / 3 - 1;
                        int cc = hc + lane % 3 - 1;
                        if (rr >= 0 && rr < Hs && cc >= 0 && cc < Hs)
                            A[rr * Hs + cc] = 0.f;
                    }
                }
            }
            __threadfence_block();   // order ds_writes before next round's reads
        }
    }
}

// grid = 128 (b = blk&63, type = blk>>6), 256 threads, ~25 KB LDS.
__global__ __launch_bounds__(256) void peaks_kernel(const float4* __restrict__ S4g,
                                                    const int* __restrict__ scale,
                                                    float* __restrict__ out) {
    __shared__ float S[HW];
    __shared__ float A[3025];
    const int blk = blockIdx.x;
    const int b   = blk & 63;
    const int tid = threadIdx.x;

    // stage S (L2/L3-warm, 12.5 KB)
    {
        float4* S4 = reinterpret_cast<float4*>(S);
        const float4* src = S4g + (size_t)b * HW4;
        for (int i = tid; i < HW4; i += 256)
            S4[i] = src[i];
    }
    __syncthreads();

    if (blk < 64) peaks_body<0>(S, A, scale, out, b);
    else          peaks_body<1>(S, A, scale, out, b);
}

extern "C" void kernel_launch(void* const* d_in, const int* in_sizes, int n_in,
                              void* d_out, int out_size, void* d_ws, size_t ws_size,
                              hipStream_t stream) {
    const float* fm    = (const float*)d_in[0];
    const int*   scale = (const int*)d_in[1];
    float*       out   = (float*)d_out;
    float*       Sbuf  = (float*)d_ws;    // 800 KB channel-sum map

    hipLaunchKernelGGL(chansum_kernel, dim3(NF4 / 256), dim3(256), 0, stream,
                       (const float4*)fm, (float4*)Sbuf);
    hipLaunchKernelGGL(peaks_kernel, dim3(2 * B), dim3(256), 0, stream,
                       (const float4*)Sbuf, scale, out);
}

// Round 10
// 31.140 us; speedup vs baseline: 2.8920x; 1.0129x over previous
//
#include <hip/hip_runtime.h>

#define B   64
#define C   128
#define H   56
#define HW  3136      // 56*56
#define HW4 784       // HW/4
#define NF4 (B * HW4) // 50176 float4 S-elements total
#define NEG_INF (-3.402823466e38f)

// ---------------- Kernel 1: direct channel sum (at HBM roofline, R6 probe) --
__global__ __launch_bounds__(256) void chansum_kernel(const float4* __restrict__ fm,
                                                      float4* __restrict__ S4) {
    int flat = blockIdx.x * 256 + threadIdx.x;     // 0..50175
    int b = flat / HW4;
    int g = flat - b * HW4;
    const float4* base = fm + (size_t)b * C * HW4 + g;
    float x = 0.f, y = 0.f, z = 0.f, w = 0.f;
    #pragma unroll 8
    for (int c = 0; c < C; ++c) {
        float4 v = base[(size_t)c * HW4];
        x += v.x; y += v.y; z += v.z; w += v.w;
    }
    S4[flat] = make_float4(x, y, z, w);
}

// ---------------- Kernel 2: LDS pooled map + small-code rounds --------------
// 512 threads: build phase halved vs R9. All loops runtime -> few-KB code
// (R8 showed the unrolled variant was I-fetch-bound at ~20 us).
template<int TYPE>
__device__ void peaks_body(const float* __restrict__ S, float* __restrict__ A,
                           const int* __restrict__ scale,
                           float* __restrict__ out, int b) {
    constexpr int K    = (TYPE == 0) ? 3 : 2;
    constexpr int Hs   = H - K + 1;              // 54 / 55
    constexpr int n    = Hs * Hs;                // 2916 / 3025
    constexpr int half = (TYPE == 0) ? 112 : 56;
    constexpr int NJ   = (n + 63) / 64;          // 46 / 48

    const int tid = threadIdx.x;

    // pooled map in LDS; per-cell dr-major add order bit-identical to the
    // verified pipeline; true IEEE division by K*K.
    for (int i = tid; i < n; i += 512) {
        int r = i / Hs, c = i - (i / Hs) * Hs;
        float s = 0.f;
        for (int dr = 0; dr < K; ++dr)
            for (int dc = 0; dc < K; ++dc)
                s += S[(r + dr) * H + (c + dc)];
        A[i] = s / (float)(K * K);
    }
    __syncthreads();

    if (tid >= 64) return;            // wave 0 runs the rounds; 1-7 retire
    const int lane = tid;

    for (int p = 0; p < 3; ++p) {
        // argmax scan (strict '>' + ascending index = first occurrence)
        float bv = NEG_INF; int bi = 0x7fffffff;
        for (int j = 0; j < NJ; ++j) {
            int i = lane + 64 * j;
            float v = (i < n) ? A[i] : NEG_INF;
            if (v > bv) { bv = v; bi = i; }
        }
        // 64-lane butterfly, tie-break min index (verified R3-R9)
        #pragma unroll
        for (int d = 1; d < 64; d <<= 1) {
            float ov = __shfl_xor(bv, d);
            int   oi = __shfl_xor(bi, d);
            if (ov > bv || (ov == bv && oi < bi)) { bv = ov; bi = oi; }
        }
        const float vmax = bv;
        const int   idx  = bi;

        if (lane == 0) {
            int lr = idx / Hs, lc = idx - (idx / Hs) * Hs;
            int pg = TYPE * 3 + p;
            out[1536 + (b * 6 + pg) * 2 + 0] = (float)lr;
            out[1536 + (b * 6 + pg) * 2 + 1] = (float)lc;
            out[2304 + b * 6 + pg] = vmax;

            int s0 = scale[b * 2 + 0], s1 = scale[b * 2 + 1];
            int smin = s0 < s1 ? s0 : s1;
            int sb0 = (s0 - smin) >> 1, sb1 = (s1 - smin) >> 1;
            float rate_h = (float)(2 * lr + H - Hs + 1) / (2.0f * H);
            float rate_w = (float)(2 * lc + H - Hs + 1) / (2.0f * H);
            int c0 = (int)__fadd_rn((float)sb0, __fmul_rn((float)smin, rate_h));
            int c1 = (int)__fadd_rn((float)sb1, __fmul_rn((float)smin, rate_w));
            int top = c0 - half, bot = c0 + half;
            int lef = c1 - half, rig = c1 + half;
            int bel0 = top < 0 ? top : 0, bel1 = lef < 0 ? lef : 0;
            top -= bel0; bot -= bel0; lef -= bel1; rig -= bel1;
            int ov0 = (bot - s0 > 0) ? (bot - s0) : 0;
            int ov1 = (rig - s1 > 0) ? (rig - s1) : 0;
            top = (top - ov0 > 0) ? (top - ov0) : 0;
            lef = (lef - ov1 > 0) ? (lef - ov1) : 0;
            bot -= ov0; rig -= ov1;
            float* il = out + (size_t)(b * 6 + pg) * 4;
            il[0] = (float)top; il[1] = (float)lef;
            il[2] = (float)bot; il[3] = (float)rig;
        }

        if (p < 2) {
            // pass 1: per-lane equality mask, read strictly PRE-erase
            unsigned long long mymask = 0ull;
            for (int j = 0; j < NJ; ++j) {
                int i = lane + 64 * j;
                if (i < n && A[i] == vmax) mymask |= (1ull << j);
            }
            // pass 2: ballot hits; 9 lanes zero the clipped 3x3 box in LDS
            for (int j = 0; j < NJ; ++j) {
                unsigned long long m = __ballot((mymask >> j) & 1ull);
                while (m) {
                    int hl = __ffsll((long long)m) - 1;
                    m &= m - 1;
                    int q  = hl + 64 * j;
                    int hr = q / Hs, hc = q - (q / Hs) * Hs;
                    if (lane < 9) {
                        int rr = hr + lane / 3 - 1;
                        int cc = hc + lane % 3 - 1;
                        if (rr >= 0 && rr < Hs && cc >= 0 && cc < Hs)
                            A[rr * Hs + cc] = 0.f;
                    }
                }
            }
            __threadfence_block();   // order ds_writes before next round's reads
        }
    }
}

// grid = 128 (b = blk&63, type = blk>>6), 512 threads, ~25 KB LDS.
__global__ __launch_bounds__(512) void peaks_kernel(const float4* __restrict__ S4g,
                                                    const int* __restrict__ scale,
                                                    float* __restrict__ out) {
    __shared__ float S[HW];
    __shared__ float A[3025];
    const int blk = blockIdx.x;
    const int b   = blk & 63;
    const int tid = threadIdx.x;

    // stage S (L2/L3-warm, 12.5 KB, 2 float4 iters at 512 threads)
    {
        float4* S4 = reinterpret_cast<float4*>(S);
        const float4* src = S4g + (size_t)b * HW4;
        for (int i = tid; i < HW4; i += 512)
            S4[i] = src[i];
    }
    __syncthreads();

    if (blk < 64) peaks_body<0>(S, A, scale, out, b);
    else          peaks_body<1>(S, A, scale, out, b);
}

extern "C" void kernel_launch(void* const* d_in, const int* in_sizes, int n_in,
                              void* d_out, int out_size, void* d_ws, size_t ws_size,
                              hipStream_t stream) {
    const float* fm    = (const float*)d_in[0];
    const int*   scale = (const int*)d_in[1];
    float*       out   = (float*)d_out;
    float*       Sbuf  = (float*)d_ws;    // 800 KB channel-sum map

    hipLaunchKernelGGL(chansum_kernel, dim3(NF4 / 256), dim3(256), 0, stream,
                       (const float4*)fm, (float4*)Sbuf);
    hipLaunchKernelGGL(peaks_kernel, dim3(2 * B), dim3(512), 0, stream,
                       (const float4*)Sbuf, scale, out);
}